// Round 1
// baseline (896.011 us; speedup 1.0000x reference)
//
#include <hip/hip_runtime.h>
#include <hip/hip_bf16.h>

// Problem: multi-adapter batched LoRA
// B=16, S=1024, H=4096, O=4096, N=8, R=64; all fp32.
// out = result + ((data*mask)*scal[n]) @ A_n^T @ B_n^T, adapter n owns 2048 rows.

#define B_   16
#define S_   1024
#define H_   4096
#define O_   4096
#define N_   8
#define R_   64
#define ROWS (B_ * S_)                 // 16384
#define ROWS_PER_ADAPTER (ROWS / N_)   // 2048
#define KSPLIT 2
#define KRANGE (H_ / KSPLIT)           // 2048

typedef __attribute__((ext_vector_type(8))) short s8v;  // 8 bf16 (4 VGPRs) - MFMA A/B frag
typedef __attribute__((ext_vector_type(4))) float f4v;  // MFMA C/D frag

// round-to-nearest-even fp32 -> bf16 (bit pattern in a short)
static __device__ __forceinline__ short f2bf(float f) {
    union { float f; unsigned u; } v; v.f = f;
    unsigned r = (v.u + 0x7FFFu + ((v.u >> 16) & 1u)) >> 16;
    return (short)r;
}

// ---------------------------------------------------------------------------
// Prologue: convert lora_a (x scaling folded in) and lora_b to bf16 in ws.
// A elems = N*R*H = 2M, B elems = N*O*R = 2M. 4 elems/thread -> 1M threads.
__global__ void cvt_weights(const float* __restrict__ la,
                            const float* __restrict__ lb,
                            const float* __restrict__ scal,
                            short* __restrict__ abf,
                            short* __restrict__ bbf) {
    const int i = blockIdx.x * blockDim.x + threadIdx.x;   // float4 index
    const int A_ELEMS4 = (N_ * R_ * H_) / 4;               // 524288
    if (i < A_ELEMS4) {
        const int n = i / ((R_ * H_) / 4);                 // i / 65536
        const float s = scal[n];
        float4 v = ((const float4*)la)[i];
        short4 o;
        o.x = f2bf(v.x * s); o.y = f2bf(v.y * s);
        o.z = f2bf(v.z * s); o.w = f2bf(v.w * s);
        ((short4*)abf)[i] = o;
    } else {
        const int j = i - A_ELEMS4;
        float4 v = ((const float4*)lb)[j];
        short4 o;
        o.x = f2bf(v.x); o.y = f2bf(v.y);
        o.z = f2bf(v.z); o.w = f2bf(v.w);
        ((short4*)bbf)[j] = o;
    }
}

// ---------------------------------------------------------------------------
// K1: t-partials[split][row][r] = sum_{k in split range} (data*mask)[row][k] * Abf[n][r][k]
// Block: 256 thr = 4 waves; wave owns 16 rows, all 64 r. Grid: (256 row-tiles, 2 splits).
// No LDS: MFMA frags loaded straight from global (16 rows x 128B lines, fully coalesced).
__global__ __launch_bounds__(256, 2)
void lora_k1(const float* __restrict__ data, const float* __restrict__ mask,
             const short* __restrict__ abf, float* __restrict__ tpart) {
    const int tile  = blockIdx.x;          // 0..255
    const int split = blockIdx.y;          // 0..1
    const int w    = threadIdx.x >> 6;     // wave 0..3
    const int lane = threadIdx.x & 63;
    const int ml   = lane & 15;            // A-frag: m index / B-frag: n index
    const int g    = lane >> 4;            // quad -> k offset g*8

    const int row0 = tile * 64;
    const int n    = row0 / ROWS_PER_ADAPTER;
    const int row  = row0 + w * 16 + ml;   // this lane's data row

    const float* dptr = data + (size_t)row * H_ + split * KRANGE + g * 8;
    const float* mptr = mask + (size_t)row * H_ + split * KRANGE + g * 8;
    const short* ap0 = abf + ((size_t)(n * R_ +  0 + ml)) * H_ + split * KRANGE + g * 8;
    const short* ap1 = abf + ((size_t)(n * R_ + 16 + ml)) * H_ + split * KRANGE + g * 8;
    const short* ap2 = abf + ((size_t)(n * R_ + 32 + ml)) * H_ + split * KRANGE + g * 8;
    const short* ap3 = abf + ((size_t)(n * R_ + 48 + ml)) * H_ + split * KRANGE + g * 8;

    f4v acc0 = {0.f, 0.f, 0.f, 0.f};
    f4v acc1 = {0.f, 0.f, 0.f, 0.f};
    f4v acc2 = {0.f, 0.f, 0.f, 0.f};
    f4v acc3 = {0.f, 0.f, 0.f, 0.f};

#pragma unroll 2
    for (int ks = 0; ks < KRANGE / 32; ++ks) {
        float4 d0 = *(const float4*)(dptr);
        float4 d1 = *(const float4*)(dptr + 4);
        float4 m0 = *(const float4*)(mptr);
        float4 m1 = *(const float4*)(mptr + 4);
        s8v a0 = *(const s8v*)(ap0);
        s8v a1 = *(const s8v*)(ap1);
        s8v a2 = *(const s8v*)(ap2);
        s8v a3 = *(const s8v*)(ap3);

        s8v xf;
        xf[0] = f2bf(d0.x * m0.x); xf[1] = f2bf(d0.y * m0.y);
        xf[2] = f2bf(d0.z * m0.z); xf[3] = f2bf(d0.w * m0.w);
        xf[4] = f2bf(d1.x * m1.x); xf[5] = f2bf(d1.y * m1.y);
        xf[6] = f2bf(d1.z * m1.z); xf[7] = f2bf(d1.w * m1.w);

        acc0 = __builtin_amdgcn_mfma_f32_16x16x32_bf16(xf, a0, acc0, 0, 0, 0);
        acc1 = __builtin_amdgcn_mfma_f32_16x16x32_bf16(xf, a1, acc1, 0, 0, 0);
        acc2 = __builtin_amdgcn_mfma_f32_16x16x32_bf16(xf, a2, acc2, 0, 0, 0);
        acc3 = __builtin_amdgcn_mfma_f32_16x16x32_bf16(xf, a3, acc3, 0, 0, 0);

        dptr += 32; mptr += 32;
        ap0 += 32; ap1 += 32; ap2 += 32; ap3 += 32;
    }

    // C/D layout (16x16x32): col = lane&15, row = (lane>>4)*4 + reg
    float* tp = tpart + ((size_t)split * ROWS + row0 + w * 16) * R_;
#pragma unroll
    for (int i = 0; i < 4; ++i) {
        tp[(g * 4 + i) * R_ +  0 + ml] = acc0[i];
        tp[(g * 4 + i) * R_ + 16 + ml] = acc1[i];
        tp[(g * 4 + i) * R_ + 32 + ml] = acc2[i];
        tp[(g * 4 + i) * R_ + 48 + ml] = acc3[i];
    }
}

// ---------------------------------------------------------------------------
// K2: out[row][o] = result[row][o] + sum_r t[row][r] * Bbf[n][o][r]
// Block: 256 thr = 4 waves; block owns 64 rows x 2048-col O-half.
// Grid: (256 row-tiles, 2 o-halves).
__global__ __launch_bounds__(256, 2)
void lora_k2(const float* __restrict__ result, const float* __restrict__ tpart,
             const short* __restrict__ bbf, float* __restrict__ out) {
    __shared__ short tlds[64 * 80];        // 64 rows x (64 r + 16 pad), 16B-aligned rows

    const int tile = blockIdx.x;
    const int oh   = blockIdx.y;
    const int tid  = threadIdx.x;
    const int row0 = tile * 64;
    const int n    = row0 / ROWS_PER_ADAPTER;

    // reduce the two K-split partials -> bf16 t in LDS
    {
        const float* p0 = tpart + (size_t)row0 * R_;
        const float* p1 = tpart + (size_t)ROWS * R_ + (size_t)row0 * R_;
#pragma unroll
        for (int i = 0; i < 4; ++i) {
            const int e  = tid + i * 256;   // float4 index into [64][16]
            const int rw = e >> 4;
            const int r4 = e & 15;
            float4 a = ((const float4*)p0)[e];
            float4 b = ((const float4*)p1)[e];
            short4 o;
            o.x = f2bf(a.x + b.x); o.y = f2bf(a.y + b.y);
            o.z = f2bf(a.z + b.z); o.w = f2bf(a.w + b.w);
            *(short4*)&tlds[rw * 80 + r4 * 4] = o;
        }
    }
    __syncthreads();

    const int w    = tid >> 6;
    const int lane = tid & 63;
    const int ml   = lane & 15;
    const int g    = lane >> 4;

    // the wave's two t A-frags (rows w*16..w*16+15, k = r), held in regs for all o-tiles
    s8v tf0 = *(const s8v*)&tlds[(w * 16 + ml) * 80 + g * 8];
    s8v tf1 = *(const s8v*)&tlds[(w * 16 + ml) * 80 + g * 8 + 32];

    // B-frag: lane n-index = o_local = ml, k = r = g*8+j; Bbf row-major [n][o][r]
    const short* bptr = bbf + ((size_t)n * O_ + oh * 2048 + ml) * R_ + g * 8;

    const size_t obase0 = (size_t)(row0 + w * 16 + g * 4) * O_ + oh * 2048 + ml;

#pragma unroll 2
    for (int ot = 0; ot < 128; ++ot) {
        s8v bf0 = *(const s8v*)(bptr);
        s8v bf1 = *(const s8v*)(bptr + 32);
        f4v acc = {0.f, 0.f, 0.f, 0.f};
        acc = __builtin_amdgcn_mfma_f32_16x16x32_bf16(tf0, bf0, acc, 0, 0, 0);
        acc = __builtin_amdgcn_mfma_f32_16x16x32_bf16(tf1, bf1, acc, 0, 0, 0);

        const size_t base = obase0 + ot * 16;
#pragma unroll
        for (int i = 0; i < 4; ++i) {
            out[base + (size_t)i * O_] = result[base + (size_t)i * O_] + acc[i];
        }
        bptr += 16 * R_;   // next 16 o-rows
    }
}

// ---------------------------------------------------------------------------
extern "C" void kernel_launch(void* const* d_in, const int* in_sizes, int n_in,
                              void* d_out, int out_size, void* d_ws, size_t ws_size,
                              hipStream_t stream) {
    const float* result = (const float*)d_in[0];
    const float* data   = (const float*)d_in[1];
    const float* mask   = (const float*)d_in[2];
    const float* lora_a = (const float*)d_in[3];
    const float* lora_b = (const float*)d_in[4];
    const float* scal   = (const float*)d_in[5];
    float* out = (float*)d_out;

    // ws layout: A_bf16 (4MB) | B_bf16 (4MB) | t-partials [2][16384][64] fp32 (8MB)
    short* abf   = (short*)d_ws;
    short* bbf   = abf + (size_t)N_ * R_ * H_;
    float* tpart = (float*)(bbf + (size_t)N_ * O_ * R_);

    const int cvt_threads = (N_ * R_ * H_ + N_ * O_ * R_) / 4;   // 1M
    cvt_weights<<<cvt_threads / 256, 256, 0, stream>>>(lora_a, lora_b, scal, abf, bbf);
    lora_k1<<<dim3(ROWS / 64, KSPLIT), 256, 0, stream>>>(data, mask, abf, tpart);
    lora_k2<<<dim3(ROWS / 64, 2), 256, 0, stream>>>(result, tpart, bbf, out);
}